// Round 2
// baseline (900.918 us; speedup 1.0000x reference)
//
#include <hip/hip_runtime.h>
#include <hip/hip_fp16.h>

#define N_NODES 50000
#define N_EDGES 800000
#define DIM 128
#define NODE_TILES 782   // ceil(50000/64)

typedef _Float16 f16;
typedef _Float16 f16x2 __attribute__((ext_vector_type(2)));
typedef _Float16 f16x8 __attribute__((ext_vector_type(8)));
typedef float    f32x16 __attribute__((ext_vector_type(16)));

// ---------------- register-resident GEMM core ----------------
// Wave computes 32 rows x 64 cols of  OUT = X(f32) @ W^T + b.
// W fragments live in registers (from pre-converted f16 table, L2-hot);
// A fragments loaded straight from global (64B segments per lane-pair), no LDS.
// Same A/B k-map and C/D layout as the round-1-verified kernel.
__device__ __forceinline__ void gemm_core(const float* __restrict__ X, long M,
                                          const f16* __restrict__ Wh,
                                          long tile0, int rc, int ch, int l31, int g,
                                          f32x16 acc[2]) {
  f16x8 bf[2][8];
#pragma unroll
  for (int c = 0; c < 2; ++c)
#pragma unroll
    for (int ks = 0; ks < 8; ++ks)
      bf[c][ks] = *(const f16x8*)(Wh + ((ch * 64 + c * 32 + l31) << 7) + 16 * ks + 8 * g);

  long row = tile0 + rc * 32 + l31;
  long gr = row < M ? row : (M - 1);          // clamp: junk rows discarded at store
  const float* xp = X + gr * DIM + 8 * g;

  float4 av0[8], av1[8];
#pragma unroll
  for (int ks = 0; ks < 8; ++ks) {
    av0[ks] = *(const float4*)(xp + 16 * ks);
    av1[ks] = *(const float4*)(xp + 16 * ks + 4);
  }

#pragma unroll
  for (int c = 0; c < 2; ++c)
#pragma unroll
    for (int k = 0; k < 16; ++k) acc[c][k] = 0.0f;

#pragma unroll
  for (int ks = 0; ks < 8; ++ks) {
    f16x8 a;
    a[0] = (f16)av0[ks].x; a[1] = (f16)av0[ks].y; a[2] = (f16)av0[ks].z; a[3] = (f16)av0[ks].w;
    a[4] = (f16)av1[ks].x; a[5] = (f16)av1[ks].y; a[6] = (f16)av1[ks].z; a[7] = (f16)av1[ks].w;
    acc[0] = __builtin_amdgcn_mfma_f32_32x32x16_f16(a, bf[0][ks], acc[0], 0, 0, 0);
    acc[1] = __builtin_amdgcn_mfma_f32_32x32x16_f16(a, bf[1][ks], acc[1], 0, 0, 0);
  }
}

template <int HALF_OUT, int SILU>
__device__ __forceinline__ void gemm_store(f32x16 acc[2], long M, const float* __restrict__ Bv,
                                           void* __restrict__ OUT,
                                           long tile0, int rc, int ch, int l31, int g) {
#pragma unroll
  for (int c = 0; c < 2; ++c) {
    int col = ch * 64 + c * 32 + l31;
    float bv = Bv[col];
#pragma unroll
    for (int r = 0; r < 16; ++r) {
      long gm = tile0 + rc * 32 + ((r & 3) + 8 * (r >> 2) + 4 * g);
      if (gm < M) {
        float v = acc[c][r] + bv;
        if (SILU) v = v / (1.0f + __expf(-v));
        if (HALF_OUT) ((f16*)OUT)[gm * DIM + col] = (f16)v;
        else          ((float*)OUT)[gm * DIM + col] = v;
      }
    }
  }
}

template <int HALF_OUT, int SILU>
__global__ __launch_bounds__(256) void gemm_v2(const float* __restrict__ X, long M,
                                               const f16* __restrict__ Wh,
                                               const float* __restrict__ Bv,
                                               void* __restrict__ OUT) {
  int lane = threadIdx.x & 63, w = threadIdx.x >> 6;
  int rc = w >> 1, ch = w & 1, l31 = lane & 31, g = lane >> 5;
  long tile0 = (long)blockIdx.x * 64;
  f32x16 acc[2];
  gemm_core(X, M, Wh, tile0, rc, ch, l31, g, acc);
  gemm_store<HALF_OUT, SILU>(acc, M, Bv, OUT, tile0, rc, ch, l31, g);
}

// Q/K/V/skip in one launch: 4 weight mats, X shared via L3.
__global__ __launch_bounds__(256) void gemm_node4(const float* __restrict__ X,
    const f16* __restrict__ WhAll,
    const float* __restrict__ bq, const float* __restrict__ bk,
    const float* __restrict__ bv_, const float* __restrict__ bs,
    f16* __restrict__ Q, f16* __restrict__ K, f16* __restrict__ V, float* __restrict__ S) {
  int mat = blockIdx.x / NODE_TILES;
  long tile0 = (long)(blockIdx.x % NODE_TILES) * 64;
  int lane = threadIdx.x & 63, w = threadIdx.x >> 6;
  int rc = w >> 1, ch = w & 1, l31 = lane & 31, g = lane >> 5;
  const f16* Wh = WhAll + mat * 16384;
  const float* Bv = (mat == 0) ? bq : (mat == 1) ? bk : (mat == 2) ? bv_ : bs;
  f32x16 acc[2];
  gemm_core(X, (long)N_NODES, Wh, tile0, rc, ch, l31, g, acc);
  if (mat == 0)      gemm_store<1, 0>(acc, N_NODES, Bv, Q, tile0, rc, ch, l31, g);
  else if (mat == 1) gemm_store<1, 0>(acc, N_NODES, Bv, K, tile0, rc, ch, l31, g);
  else if (mat == 2) gemm_store<1, 0>(acc, N_NODES, Bv, V, tile0, rc, ch, l31, g);
  else               gemm_store<0, 0>(acc, N_NODES, Bv, S, tile0, rc, ch, l31, g);
}

// convert all 7 weight matrices f32 -> f16, one launch
__global__ void convert7(const float* __restrict__ a0, const float* __restrict__ a1,
                         const float* __restrict__ a2, const float* __restrict__ a3,
                         const float* __restrict__ a4, const float* __restrict__ a5,
                         const float* __restrict__ a6, f16* __restrict__ dst) {
  int i = blockIdx.x * blockDim.x + threadIdx.x;  // grid 112*1024 = 7*16384
  int mat = i >> 14, el = i & 16383;
  const float* s = (mat == 0) ? a0 : (mat == 1) ? a1 : (mat == 2) ? a2 : (mat == 3) ? a3
                 : (mat == 4) ? a4 : (mat == 5) ? a5 : a6;
  dst[i] = (f16)s[el];
}

// ---------------- CSR build ----------------
__global__ void hist_k(const int* __restrict__ ei, int* __restrict__ counts) {
  for (long e = blockIdx.x * (long)blockDim.x + threadIdx.x; e < N_EDGES;
       e += (long)gridDim.x * blockDim.x)
    atomicAdd(&counts[ei[N_EDGES + e]], 1);
}

__global__ __launch_bounds__(1024) void scan_k(const int* __restrict__ counts,
                                               int* __restrict__ offs, int* __restrict__ cursor) {
  __shared__ int sd[1024];
  int tid = threadIdx.x;
  const int CH = (N_NODES + 1023) / 1024;
  int i0 = tid * CH;
  int s = 0;
  for (int i = 0; i < CH; ++i) { int idx = i0 + i; if (idx < N_NODES) s += counts[idx]; }
  sd[tid] = s; __syncthreads();
  for (int off = 1; off < 1024; off <<= 1) {
    int v = (tid >= off) ? sd[tid - off] : 0;
    __syncthreads();
    sd[tid] += v;
    __syncthreads();
  }
  int run = sd[tid] - s;
  for (int i = 0; i < CH; ++i) {
    int idx = i0 + i;
    if (idx < N_NODES) { offs[idx] = run; cursor[idx] = run; run += counts[idx]; }
  }
  if (tid == 1023) offs[N_NODES] = run;
}

__global__ void scatter_k(const int* __restrict__ ei, int* __restrict__ cursor,
                          int* __restrict__ elist) {
  for (long e = blockIdx.x * (long)blockDim.x + threadIdx.x; e < N_EDGES;
       e += (long)gridDim.x * blockDim.x) {
    int d = ei[N_EDGES + e];
    int pos = atomicAdd(&cursor[d], 1);
    elist[pos] = (int)e;
  }
}

// ---------------- attention edge/softmax kernels ----------------
__global__ __launch_bounds__(256) void edge_alpha(const int* __restrict__ ei,
    const f16* __restrict__ Qn, const f16* __restrict__ Kn, const f16* __restrict__ emat,
    float* __restrict__ exo) {
  int lane = threadIdx.x & 63;
  long wid = (blockIdx.x * 256L + threadIdx.x) >> 6;
  long nw = (gridDim.x * 256L) >> 6;
  for (long e = wid; e < N_EDGES; e += nw) {
    int s = ei[e], d = ei[N_EDGES + e];
    f16x2 q2 = *(const f16x2*)(Qn + (long)d * DIM + 2 * lane);
    f16x2 k2 = *(const f16x2*)(Kn + (long)s * DIM + 2 * lane);
    f16x2 e2 = *(const f16x2*)(emat + e * DIM + 2 * lane);
    float p = (float)q2[0] * ((float)k2[0] + (float)e2[0]) +
              (float)q2[1] * ((float)k2[1] + (float)e2[1]);
    p += __shfl_xor(p, 1);
    p += __shfl_xor(p, 2);
    p += __shfl_xor(p, 4);
    float ex = __expf(p * 0.25f);
    if ((lane & 7) == 0) exo[e * 8 + (lane >> 3)] = ex;
  }
}

// per dst node: out = sum(ex*(e+V[src]))/sum(ex); index chain prefetched 1 ahead
__global__ __launch_bounds__(256) void attn_gather(const int* __restrict__ ei,
    const int* __restrict__ offs, const int* __restrict__ elist, const float* __restrict__ exv,
    const f16* __restrict__ emat, const f16* __restrict__ Vn, float* __restrict__ outp) {
  int n = blockIdx.x * 4 + (threadIdx.x >> 6);
  if (n >= N_NODES) return;
  int lane = threadIdx.x & 63;
  int h = lane >> 3;
  int rs = offs[n], re = offs[n + 1];
  float a0 = 0.f, a1 = 0.f, den = 0.f;
  int eid_n = 0, s_n = 0;
  if (rs < re) { eid_n = elist[rs]; s_n = ei[eid_n]; }
  for (int i = rs; i < re; ++i) {
    int eid = eid_n, s = s_n;
    if (i + 1 < re) { eid_n = elist[i + 1]; s_n = ei[eid_n]; }
    float exh = exv[(long)eid * 8 + h];
    f16x2 e2 = *(const f16x2*)(emat + (long)eid * DIM + 2 * lane);
    f16x2 v2 = *(const f16x2*)(Vn + (long)s * DIM + 2 * lane);
    a0 += exh * ((float)e2[0] + (float)v2[0]);
    a1 += exh * ((float)e2[1] + (float)v2[1]);
    den += exh;
  }
  float inv = 1.f / (den + 1e-16f);
  float2 o; o.x = a0 * inv; o.y = a1 * inv;
  *(float2*)(outp + (long)n * DIM + 2 * lane) = o;
}

// out = base + LN(xa [+ xb]) * g + b
__global__ __launch_bounds__(256) void post_ln(const float* __restrict__ xa,
    const float* __restrict__ xb, const float* __restrict__ base,
    const float* __restrict__ g, const float* __restrict__ b, float* __restrict__ outp) {
  int n = blockIdx.x * 4 + (threadIdx.x >> 6);
  if (n >= N_NODES) return;
  int lane = threadIdx.x & 63;
  float2 x = *(const float2*)(xa + (long)n * DIM + 2 * lane);
  if (xb) {
    float2 y = *(const float2*)(xb + (long)n * DIM + 2 * lane);
    x.x += y.x; x.y += y.y;
  }
  float sm = x.x + x.y;
  for (int m = 1; m < 64; m <<= 1) sm += __shfl_xor(sm, m);
  float mu = sm * (1.f / 128.f);
  float dx = x.x - mu, dy = x.y - mu;
  float ss = dx * dx + dy * dy;
  for (int m = 1; m < 64; m <<= 1) ss += __shfl_xor(ss, m);
  float r = rsqrtf(ss * (1.f / 128.f) + 1e-5f);
  float2 gg = *(const float2*)(g + 2 * lane);
  float2 bb = *(const float2*)(b + 2 * lane);
  float2 bs = *(const float2*)(base + (long)n * DIM + 2 * lane);
  float2 o;
  o.x = bs.x + dx * r * gg.x + bb.x;
  o.y = bs.y + dy * r * gg.y + bb.y;
  *(float2*)(outp + (long)n * DIM + 2 * lane) = o;
}

// ---------------- launch ----------------
extern "C" void kernel_launch(void* const* d_in, const int* in_sizes, int n_in,
                              void* d_out, int out_size, void* d_ws, size_t ws_size,
                              hipStream_t stream) {
  (void)in_sizes; (void)n_in; (void)out_size; (void)ws_size;
  const int*   ei  = (const int*)d_in[0];
  const float* x0  = (const float*)d_in[1];
  const float* ea  = (const float*)d_in[2];
  const float* Wq  = (const float*)d_in[3];  const float* bq = (const float*)d_in[4];
  const float* Wk  = (const float*)d_in[5];  const float* bk = (const float*)d_in[6];
  const float* Wv  = (const float*)d_in[7];  const float* bv = (const float*)d_in[8];
  const float* We  = (const float*)d_in[9];  const float* be = (const float*)d_in[10];
  const float* Wsk = (const float*)d_in[11]; const float* bsk = (const float*)d_in[12];
  const float* W1  = (const float*)d_in[13]; const float* b1 = (const float*)d_in[14];
  const float* W2  = (const float*)d_in[15]; const float* b2 = (const float*)d_in[16];
  const float* g1  = (const float*)d_in[17]; const float* lb1 = (const float*)d_in[18];
  const float* g2  = (const float*)d_in[19]; const float* lb2 = (const float*)d_in[20];

  char* ws = (char*)d_ws;
  f16*   Qn     = (f16*)(ws + 0);
  f16*   Kn     = (f16*)(ws + 12800000L);
  f16*   Vn     = (f16*)(ws + 25600000L);
  float* Skip   = (float*)(ws + 38400000L);
  float* exv    = (float*)(ws + 64000000L);
  int*   offs   = (int*)(ws + 89600000L);
  f16*   WhAll  = (f16*)(ws + 89800192L);    // 229376 B; overlays cursor+counts (dead after CSR build)
  int*   cursor = (int*)(ws + 89800192L);
  int*   counts = (int*)(ws + 90030592L);
  int*   elist  = (int*)(ws + 90230784L);
  f16*   emat   = (f16*)(ws + 93430784L);
  float* node1  = (float*)(ws + 298230784L);
  float* hid    = (float*)(ws + 38400000L);  // reuse Skip (dead after post_ln1)
  float* h2     = (float*)(ws + 0);          // reuse Qn/Kn (dead after edge_alpha)
  float* attn   = (float*)d_out;             // staging; overwritten by final post_ln

  hipMemsetAsync(counts, 0, N_NODES * sizeof(int), stream);
  hist_k<<<1024, 256, 0, stream>>>(ei, counts);
  scan_k<<<1, 1024, 0, stream>>>(counts, offs, cursor);
  scatter_k<<<1024, 256, 0, stream>>>(ei, cursor, elist);
  convert7<<<112, 1024, 0, stream>>>(Wq, Wk, Wv, Wsk, We, W1, W2, WhAll);

  gemm_node4<<<4 * NODE_TILES, 256, 0, stream>>>(x0, WhAll, bq, bk, bv, bsk, Qn, Kn, Vn, Skip);
  gemm_v2<1, 0><<<N_EDGES / 64, 256, 0, stream>>>(ea, (long)N_EDGES, WhAll + 4 * 16384, be, emat);
  edge_alpha<<<4096, 256, 0, stream>>>(ei, Qn, Kn, emat, exv);
  attn_gather<<<12500, 256, 0, stream>>>(ei, offs, elist, exv, emat, Vn, attn);
  post_ln<<<12500, 256, 0, stream>>>(attn, Skip, x0, g1, lb1, node1);
  gemm_v2<0, 1><<<NODE_TILES, 256, 0, stream>>>(node1, (long)N_NODES, WhAll + 5 * 16384, b1, hid);
  gemm_v2<0, 0><<<NODE_TILES, 256, 0, stream>>>(hid, (long)N_NODES, WhAll + 6 * 16384, b2, h2);
  post_ln<<<12500, 256, 0, stream>>>(h2, nullptr, node1, g2, lb2, (float*)d_out);
}

// Round 3
// 813.636 us; speedup vs baseline: 1.1073x; 1.1073x over previous
//
#include <hip/hip_runtime.h>
#include <hip/hip_fp16.h>

#define N_NODES 50000
#define N_EDGES 800000
#define DIM 128
#define NODE_TILES 782   // ceil(50000/64)

typedef _Float16 f16;
typedef _Float16 f16x2 __attribute__((ext_vector_type(2)));
typedef _Float16 f16x8 __attribute__((ext_vector_type(8)));
typedef float    f32x16 __attribute__((ext_vector_type(16)));

__device__ __forceinline__ void sfence() { __builtin_amdgcn_sched_barrier(0); }

// ---------------- register-resident GEMM v3 ----------------
// Wave computes 32 rows x 64 cols of OUT = X(f32) @ W^T + b, W frags in regs.
// All 16 A-loads issued as one fenced cluster -> single latency exposure.
__device__ __forceinline__ void load_wfrag(const f16* __restrict__ Wh, int ch, int l31, int g,
                                           f16x8 bf[2][8]) {
#pragma unroll
  for (int c = 0; c < 2; ++c)
#pragma unroll
    for (int ks = 0; ks < 8; ++ks)
      bf[c][ks] = *(const f16x8*)(Wh + ((ch * 64 + c * 32 + l31) << 7) + 16 * ks + 8 * g);
}

__device__ __forceinline__ void issue_aloads(const float* __restrict__ xp,
                                             float4 av0[8], float4 av1[8]) {
#pragma unroll
  for (int ks = 0; ks < 8; ++ks) {
    av0[ks] = *(const float4*)(xp + 16 * ks);
    av1[ks] = *(const float4*)(xp + 16 * ks + 4);
  }
}

__device__ __forceinline__ void compute_tile(const float4 av0[8], const float4 av1[8],
                                             const f16x8 bf[2][8], f32x16 acc[2]) {
#pragma unroll
  for (int c = 0; c < 2; ++c)
#pragma unroll
    for (int k = 0; k < 16; ++k) acc[c][k] = 0.0f;
#pragma unroll
  for (int ks = 0; ks < 8; ++ks) {
    f16x8 a;
    a[0] = (f16)av0[ks].x; a[1] = (f16)av0[ks].y; a[2] = (f16)av0[ks].z; a[3] = (f16)av0[ks].w;
    a[4] = (f16)av1[ks].x; a[5] = (f16)av1[ks].y; a[6] = (f16)av1[ks].z; a[7] = (f16)av1[ks].w;
    acc[0] = __builtin_amdgcn_mfma_f32_32x32x16_f16(a, bf[0][ks], acc[0], 0, 0, 0);
    acc[1] = __builtin_amdgcn_mfma_f32_32x32x16_f16(a, bf[1][ks], acc[1], 0, 0, 0);
  }
}

template <int HALF_OUT, int SILU>
__device__ __forceinline__ void gemm_store(f32x16 acc[2], long M, const float* __restrict__ Bv,
                                           void* __restrict__ OUT,
                                           long tile0, int rc, int ch, int l31, int g) {
#pragma unroll
  for (int c = 0; c < 2; ++c) {
    int col = ch * 64 + c * 32 + l31;
    float bv = Bv[col];
#pragma unroll
    for (int r = 0; r < 16; ++r) {
      long gm = tile0 + rc * 32 + ((r & 3) + 8 * (r >> 2) + 4 * g);
      if (gm < M) {
        float v = acc[c][r] + bv;
        if (SILU) v = v / (1.0f + __expf(-v));
        if (HALF_OUT) ((f16*)OUT)[gm * DIM + col] = (f16)v;
        else          ((float*)OUT)[gm * DIM + col] = v;
      }
    }
  }
}

template <int HALF_OUT, int SILU>
__global__ __launch_bounds__(256) void gemm_v3(const float* __restrict__ X, long M, int ntiles,
                                               const f16* __restrict__ Wh,
                                               const float* __restrict__ Bv,
                                               void* __restrict__ OUT) {
  int lane = threadIdx.x & 63, w = threadIdx.x >> 6;
  int rc = w >> 1, ch = w & 1, l31 = lane & 31, g = lane >> 5;
  f16x8 bf[2][8];
  load_wfrag(Wh, ch, l31, g, bf);          // W resident for whole kernel (L2-hot)
  for (long t = blockIdx.x; t < ntiles; t += gridDim.x) {
    long tile0 = t * 64;
    long row = tile0 + rc * 32 + l31;
    long gr = row < M ? row : (M - 1);
    const float* xp = X + gr * DIM + 8 * g;
    float4 av0[8], av1[8];
    issue_aloads(xp, av0, av1);            // 16 loads, one cluster
    sfence();                              // pin: no load sinks below this point
    f32x16 acc[2];
    compute_tile(av0, av1, bf, acc);
    gemm_store<HALF_OUT, SILU>(acc, M, Bv, OUT, tile0, rc, ch, l31, g);
    sfence();
  }
}

// Q/K/V/skip fused: persistent over 4*NODE_TILES tiles; W reloaded per iter in the cluster.
__global__ __launch_bounds__(256) void node4_v3(const float* __restrict__ X,
    const f16* __restrict__ WhAll,
    const float* __restrict__ bq, const float* __restrict__ bk,
    const float* __restrict__ bv_, const float* __restrict__ bs,
    f16* __restrict__ Q, f16* __restrict__ K, f16* __restrict__ V, float* __restrict__ S) {
  int lane = threadIdx.x & 63, w = threadIdx.x >> 6;
  int rc = w >> 1, ch = w & 1, l31 = lane & 31, g = lane >> 5;
  for (int t = blockIdx.x; t < 4 * NODE_TILES; t += gridDim.x) {
    int mat = t / NODE_TILES;
    long tile0 = (long)(t - mat * NODE_TILES) * 64;
    long row = tile0 + rc * 32 + l31;
    long gr = row < N_NODES ? row : (N_NODES - 1);
    const float* xp = X + gr * DIM + 8 * g;
    float4 av0[8], av1[8];
    f16x8 bf[2][8];
    issue_aloads(xp, av0, av1);
    load_wfrag(WhAll + mat * 16384, ch, l31, g, bf);
    sfence();
    f32x16 acc[2];
    compute_tile(av0, av1, bf, acc);
    if (mat == 0) {
      gemm_store<1, 0>(acc, N_NODES, bq, Q, tile0, rc, ch, l31, g);
    } else if (mat == 1) {
      gemm_store<1, 0>(acc, N_NODES, bk, K, tile0, rc, ch, l31, g);
    } else if (mat == 2) {
      gemm_store<1, 0>(acc, N_NODES, bv_, V, tile0, rc, ch, l31, g);
    } else {
      gemm_store<0, 0>(acc, N_NODES, bs, S, tile0, rc, ch, l31, g);
    }
    sfence();
  }
}

// convert all 7 weight matrices f32 -> f16, one launch
__global__ void convert7(const float* __restrict__ a0, const float* __restrict__ a1,
                         const float* __restrict__ a2, const float* __restrict__ a3,
                         const float* __restrict__ a4, const float* __restrict__ a5,
                         const float* __restrict__ a6, f16* __restrict__ dst) {
  int i = blockIdx.x * blockDim.x + threadIdx.x;  // grid 112*1024 = 7*16384
  int mat = i >> 14, el = i & 16383;
  const float* s = (mat == 0) ? a0 : (mat == 1) ? a1 : (mat == 2) ? a2 : (mat == 3) ? a3
                 : (mat == 4) ? a4 : (mat == 5) ? a5 : a6;
  dst[i] = (f16)s[el];
}

// ---------------- CSR build ----------------
__global__ void hist_k(const int* __restrict__ ei, int* __restrict__ counts) {
  for (long e = blockIdx.x * (long)blockDim.x + threadIdx.x; e < N_EDGES;
       e += (long)gridDim.x * blockDim.x)
    atomicAdd(&counts[ei[N_EDGES + e]], 1);
}

__global__ __launch_bounds__(1024) void scan_k(const int* __restrict__ counts,
                                               int* __restrict__ offs, int* __restrict__ cursor) {
  __shared__ int sd[1024];
  int tid = threadIdx.x;
  const int CH = (N_NODES + 1023) / 1024;
  int i0 = tid * CH;
  int s = 0;
  for (int i = 0; i < CH; ++i) { int idx = i0 + i; if (idx < N_NODES) s += counts[idx]; }
  sd[tid] = s; __syncthreads();
  for (int off = 1; off < 1024; off <<= 1) {
    int v = (tid >= off) ? sd[tid - off] : 0;
    __syncthreads();
    sd[tid] += v;
    __syncthreads();
  }
  int run = sd[tid] - s;
  for (int i = 0; i < CH; ++i) {
    int idx = i0 + i;
    if (idx < N_NODES) { offs[idx] = run; cursor[idx] = run; run += counts[idx]; }
  }
  if (tid == 1023) offs[N_NODES] = run;
}

__global__ void scatter_k(const int* __restrict__ ei, int* __restrict__ cursor,
                          int* __restrict__ elist) {
  for (long e = blockIdx.x * (long)blockDim.x + threadIdx.x; e < N_EDGES;
       e += (long)gridDim.x * blockDim.x) {
    int d = ei[N_EDGES + e];
    int pos = atomicAdd(&cursor[d], 1);
    elist[pos] = (int)e;
  }
}

// ---------------- attention edge/softmax kernels ----------------
__global__ __launch_bounds__(256) void edge_alpha(const int* __restrict__ ei,
    const f16* __restrict__ Qn, const f16* __restrict__ Kn, const f16* __restrict__ emat,
    float* __restrict__ exo) {
  int lane = threadIdx.x & 63;
  long wid = (blockIdx.x * 256L + threadIdx.x) >> 6;
  long nw = (gridDim.x * 256L) >> 6;
  for (long e = wid; e < N_EDGES; e += nw) {
    int s = ei[e], d = ei[N_EDGES + e];
    f16x2 q2 = *(const f16x2*)(Qn + (long)d * DIM + 2 * lane);
    f16x2 k2 = *(const f16x2*)(Kn + (long)s * DIM + 2 * lane);
    f16x2 e2 = *(const f16x2*)(emat + e * DIM + 2 * lane);
    float p = (float)q2[0] * ((float)k2[0] + (float)e2[0]) +
              (float)q2[1] * ((float)k2[1] + (float)e2[1]);
    p += __shfl_xor(p, 1);
    p += __shfl_xor(p, 2);
    p += __shfl_xor(p, 4);
    float ex = __expf(p * 0.25f);
    if ((lane & 7) == 0) exo[e * 8 + (lane >> 3)] = ex;
  }
}

// per dst node: out = sum(ex*(e+V[src]))/sum(ex); index chain prefetched 1 ahead
__global__ __launch_bounds__(256) void attn_gather(const int* __restrict__ ei,
    const int* __restrict__ offs, const int* __restrict__ elist, const float* __restrict__ exv,
    const f16* __restrict__ emat, const f16* __restrict__ Vn, float* __restrict__ outp) {
  int n = blockIdx.x * 4 + (threadIdx.x >> 6);
  if (n >= N_NODES) return;
  int lane = threadIdx.x & 63;
  int h = lane >> 3;
  int rs = offs[n], re = offs[n + 1];
  float a0 = 0.f, a1 = 0.f, den = 0.f;
  int eid_n = 0, s_n = 0;
  if (rs < re) { eid_n = elist[rs]; s_n = ei[eid_n]; }
  for (int i = rs; i < re; ++i) {
    int eid = eid_n, s = s_n;
    if (i + 1 < re) { eid_n = elist[i + 1]; s_n = ei[eid_n]; }
    float exh = exv[(long)eid * 8 + h];
    f16x2 e2 = *(const f16x2*)(emat + (long)eid * DIM + 2 * lane);
    f16x2 v2 = *(const f16x2*)(Vn + (long)s * DIM + 2 * lane);
    a0 += exh * ((float)e2[0] + (float)v2[0]);
    a1 += exh * ((float)e2[1] + (float)v2[1]);
    den += exh;
  }
  float inv = 1.f / (den + 1e-16f);
  float2 o; o.x = a0 * inv; o.y = a1 * inv;
  *(float2*)(outp + (long)n * DIM + 2 * lane) = o;
}

// out = base + LN(xa [+ xb]) * g + b
__global__ __launch_bounds__(256) void post_ln(const float* __restrict__ xa,
    const float* __restrict__ xb, const float* __restrict__ base,
    const float* __restrict__ g, const float* __restrict__ b, float* __restrict__ outp) {
  int n = blockIdx.x * 4 + (threadIdx.x >> 6);
  if (n >= N_NODES) return;
  int lane = threadIdx.x & 63;
  float2 x = *(const float2*)(xa + (long)n * DIM + 2 * lane);
  if (xb) {
    float2 y = *(const float2*)(xb + (long)n * DIM + 2 * lane);
    x.x += y.x; x.y += y.y;
  }
  float sm = x.x + x.y;
  for (int m = 1; m < 64; m <<= 1) sm += __shfl_xor(sm, m);
  float mu = sm * (1.f / 128.f);
  float dx = x.x - mu, dy = x.y - mu;
  float ss = dx * dx + dy * dy;
  for (int m = 1; m < 64; m <<= 1) ss += __shfl_xor(ss, m);
  float r = rsqrtf(ss * (1.f / 128.f) + 1e-5f);
  float2 gg = *(const float2*)(g + 2 * lane);
  float2 bb = *(const float2*)(b + 2 * lane);
  float2 bs = *(const float2*)(base + (long)n * DIM + 2 * lane);
  float2 o;
  o.x = bs.x + dx * r * gg.x + bb.x;
  o.y = bs.y + dy * r * gg.y + bb.y;
  *(float2*)(outp + (long)n * DIM + 2 * lane) = o;
}

// ---------------- launch ----------------
extern "C" void kernel_launch(void* const* d_in, const int* in_sizes, int n_in,
                              void* d_out, int out_size, void* d_ws, size_t ws_size,
                              hipStream_t stream) {
  (void)in_sizes; (void)n_in; (void)out_size; (void)ws_size;
  const int*   ei  = (const int*)d_in[0];
  const float* x0  = (const float*)d_in[1];
  const float* ea  = (const float*)d_in[2];
  const float* Wq  = (const float*)d_in[3];  const float* bq = (const float*)d_in[4];
  const float* Wk  = (const float*)d_in[5];  const float* bk = (const float*)d_in[6];
  const float* Wv  = (const float*)d_in[7];  const float* bv = (const float*)d_in[8];
  const float* We  = (const float*)d_in[9];  const float* be = (const float*)d_in[10];
  const float* Wsk = (const float*)d_in[11]; const float* bsk = (const float*)d_in[12];
  const float* W1  = (const float*)d_in[13]; const float* b1 = (const float*)d_in[14];
  const float* W2  = (const float*)d_in[15]; const float* b2 = (const float*)d_in[16];
  const float* g1  = (const float*)d_in[17]; const float* lb1 = (const float*)d_in[18];
  const float* g2  = (const float*)d_in[19]; const float* lb2 = (const float*)d_in[20];

  char* ws = (char*)d_ws;
  f16*   Qn     = (f16*)(ws + 0);
  f16*   Kn     = (f16*)(ws + 12800000L);
  f16*   Vn     = (f16*)(ws + 25600000L);
  float* Skip   = (float*)(ws + 38400000L);
  float* exv    = (float*)(ws + 64000000L);
  int*   offs   = (int*)(ws + 89600000L);
  f16*   WhAll  = (f16*)(ws + 89800192L);    // 229376 B; overlays cursor+counts (dead after CSR)
  int*   cursor = (int*)(ws + 89800192L);
  int*   counts = (int*)(ws + 90030592L);
  int*   elist  = (int*)(ws + 90230784L);
  f16*   emat   = (f16*)(ws + 93430784L);
  float* node1  = (float*)(ws + 298230784L);
  float* hid    = (float*)(ws + 38400000L);  // reuse Skip (dead after post_ln1)
  float* h2     = (float*)(ws + 0);          // reuse Qn/Kn (dead after edge_alpha)
  float* attn   = (float*)d_out;             // staging; overwritten by final post_ln

  hipMemsetAsync(counts, 0, N_NODES * sizeof(int), stream);
  hist_k<<<1024, 256, 0, stream>>>(ei, counts);
  scan_k<<<1, 1024, 0, stream>>>(counts, offs, cursor);
  scatter_k<<<1024, 256, 0, stream>>>(ei, cursor, elist);
  convert7<<<112, 1024, 0, stream>>>(Wq, Wk, Wv, Wsk, We, W1, W2, WhAll);

  node4_v3<<<1024, 256, 0, stream>>>(x0, WhAll, bq, bk, bv, bsk, Qn, Kn, Vn, Skip);
  gemm_v3<1, 0><<<2048, 256, 0, stream>>>(ea, (long)N_EDGES, N_EDGES / 64,
                                          WhAll + 4 * 16384, be, emat);
  edge_alpha<<<4096, 256, 0, stream>>>(ei, Qn, Kn, emat, exv);
  attn_gather<<<12500, 256, 0, stream>>>(ei, offs, elist, exv, emat, Vn, attn);
  post_ln<<<12500, 256, 0, stream>>>(attn, Skip, x0, g1, lb1, node1);
  gemm_v3<0, 1><<<NODE_TILES, 256, 0, stream>>>(node1, (long)N_NODES, NODE_TILES,
                                                WhAll + 5 * 16384, b1, hid);
  gemm_v3<0, 0><<<NODE_TILES, 256, 0, stream>>>(hid, (long)N_NODES, NODE_TILES,
                                                WhAll + 6 * 16384, b2, h2);
  post_ln<<<12500, 256, 0, stream>>>(h2, nullptr, node1, g2, lb2, (float*)d_out);
}

// Round 4
// 808.209 us; speedup vs baseline: 1.1147x; 1.0067x over previous
//
#include <hip/hip_runtime.h>
#include <hip/hip_fp16.h>

#define N_NODES 50000
#define N_EDGES 800000
#define DIM 128
#define NODE_TILES 782   // ceil(50000/64)

typedef _Float16 f16;
typedef _Float16 f16x2 __attribute__((ext_vector_type(2)));
typedef _Float16 f16x8 __attribute__((ext_vector_type(8)));
typedef float    f32x16 __attribute__((ext_vector_type(16)));

__device__ __forceinline__ void sfence() { __builtin_amdgcn_sched_barrier(0); }

// ---------------- register-resident GEMM v3 ----------------
// Wave computes 32 rows x 64 cols of OUT = X(f32) @ W^T + b, W frags in regs.
// All 16 A-loads issued as one fenced cluster -> single latency exposure.
__device__ __forceinline__ void load_wfrag(const f16* __restrict__ Wh, int ch, int l31, int g,
                                           f16x8 bf[2][8]) {
#pragma unroll
  for (int c = 0; c < 2; ++c)
#pragma unroll
    for (int ks = 0; ks < 8; ++ks)
      bf[c][ks] = *(const f16x8*)(Wh + ((ch * 64 + c * 32 + l31) << 7) + 16 * ks + 8 * g);
}

__device__ __forceinline__ void issue_aloads(const float* __restrict__ xp,
                                             float4 av0[8], float4 av1[8]) {
#pragma unroll
  for (int ks = 0; ks < 8; ++ks) {
    av0[ks] = *(const float4*)(xp + 16 * ks);
    av1[ks] = *(const float4*)(xp + 16 * ks + 4);
  }
}

__device__ __forceinline__ void compute_tile(const float4 av0[8], const float4 av1[8],
                                             const f16x8 bf[2][8], f32x16 acc[2]) {
#pragma unroll
  for (int c = 0; c < 2; ++c)
#pragma unroll
    for (int k = 0; k < 16; ++k) acc[c][k] = 0.0f;
#pragma unroll
  for (int ks = 0; ks < 8; ++ks) {
    f16x8 a;
    a[0] = (f16)av0[ks].x; a[1] = (f16)av0[ks].y; a[2] = (f16)av0[ks].z; a[3] = (f16)av0[ks].w;
    a[4] = (f16)av1[ks].x; a[5] = (f16)av1[ks].y; a[6] = (f16)av1[ks].z; a[7] = (f16)av1[ks].w;
    acc[0] = __builtin_amdgcn_mfma_f32_32x32x16_f16(a, bf[0][ks], acc[0], 0, 0, 0);
    acc[1] = __builtin_amdgcn_mfma_f32_32x32x16_f16(a, bf[1][ks], acc[1], 0, 0, 0);
  }
}

template <int HALF_OUT, int SILU>
__device__ __forceinline__ void gemm_store(f32x16 acc[2], long M, const float* __restrict__ Bv,
                                           void* __restrict__ OUT,
                                           long tile0, int rc, int ch, int l31, int g) {
#pragma unroll
  for (int c = 0; c < 2; ++c) {
    int col = ch * 64 + c * 32 + l31;
    float bv = Bv[col];
#pragma unroll
    for (int r = 0; r < 16; ++r) {
      long gm = tile0 + rc * 32 + ((r & 3) + 8 * (r >> 2) + 4 * g);
      if (gm < M) {
        float v = acc[c][r] + bv;
        if (SILU) v = v / (1.0f + __expf(-v));
        if (HALF_OUT) ((f16*)OUT)[gm * DIM + col] = (f16)v;
        else          ((float*)OUT)[gm * DIM + col] = v;
      }
    }
  }
}

template <int HALF_OUT, int SILU>
__global__ __launch_bounds__(256) void gemm_v3(const float* __restrict__ X, long M, int ntiles,
                                               const f16* __restrict__ Wh,
                                               const float* __restrict__ Bv,
                                               void* __restrict__ OUT) {
  int lane = threadIdx.x & 63, w = threadIdx.x >> 6;
  int rc = w >> 1, ch = w & 1, l31 = lane & 31, g = lane >> 5;
  f16x8 bf[2][8];
  load_wfrag(Wh, ch, l31, g, bf);          // W resident for whole kernel (L2-hot)
  for (long t = blockIdx.x; t < ntiles; t += gridDim.x) {
    long tile0 = t * 64;
    long row = tile0 + rc * 32 + l31;
    long gr = row < M ? row : (M - 1);
    const float* xp = X + gr * DIM + 8 * g;
    float4 av0[8], av1[8];
    issue_aloads(xp, av0, av1);            // 16 loads, one cluster
    sfence();                              // pin: no load sinks below this point
    f32x16 acc[2];
    compute_tile(av0, av1, bf, acc);
    gemm_store<HALF_OUT, SILU>(acc, M, Bv, OUT, tile0, rc, ch, l31, g);
    sfence();
  }
}

// Q/K/V/skip fused: persistent over 4*NODE_TILES tiles; W reloaded per iter in the cluster.
__global__ __launch_bounds__(256) void node4_v3(const float* __restrict__ X,
    const f16* __restrict__ WhAll,
    const float* __restrict__ bq, const float* __restrict__ bk,
    const float* __restrict__ bv_, const float* __restrict__ bs,
    f16* __restrict__ Q, f16* __restrict__ K, f16* __restrict__ V, float* __restrict__ S) {
  int lane = threadIdx.x & 63, w = threadIdx.x >> 6;
  int rc = w >> 1, ch = w & 1, l31 = lane & 31, g = lane >> 5;
  for (int t = blockIdx.x; t < 4 * NODE_TILES; t += gridDim.x) {
    int mat = t / NODE_TILES;
    long tile0 = (long)(t - mat * NODE_TILES) * 64;
    long row = tile0 + rc * 32 + l31;
    long gr = row < N_NODES ? row : (N_NODES - 1);
    const float* xp = X + gr * DIM + 8 * g;
    float4 av0[8], av1[8];
    f16x8 bf[2][8];
    issue_aloads(xp, av0, av1);
    load_wfrag(WhAll + mat * 16384, ch, l31, g, bf);
    sfence();
    f32x16 acc[2];
    compute_tile(av0, av1, bf, acc);
    if (mat == 0) {
      gemm_store<1, 0>(acc, N_NODES, bq, Q, tile0, rc, ch, l31, g);
    } else if (mat == 1) {
      gemm_store<1, 0>(acc, N_NODES, bk, K, tile0, rc, ch, l31, g);
    } else if (mat == 2) {
      gemm_store<1, 0>(acc, N_NODES, bv_, V, tile0, rc, ch, l31, g);
    } else {
      gemm_store<0, 0>(acc, N_NODES, bs, S, tile0, rc, ch, l31, g);
    }
    sfence();
  }
}

// convert all 7 weight matrices f32 -> f16, one launch
__global__ void convert7(const float* __restrict__ a0, const float* __restrict__ a1,
                         const float* __restrict__ a2, const float* __restrict__ a3,
                         const float* __restrict__ a4, const float* __restrict__ a5,
                         const float* __restrict__ a6, f16* __restrict__ dst) {
  int i = blockIdx.x * blockDim.x + threadIdx.x;  // grid 112*1024 = 7*16384
  int mat = i >> 14, el = i & 16383;
  const float* s = (mat == 0) ? a0 : (mat == 1) ? a1 : (mat == 2) ? a2 : (mat == 3) ? a3
                 : (mat == 4) ? a4 : (mat == 5) ? a5 : a6;
  dst[i] = (f16)s[el];
}

// ---------------- CSR build ----------------
__global__ void hist_k(const int* __restrict__ ei, int* __restrict__ counts) {
  for (long e = blockIdx.x * (long)blockDim.x + threadIdx.x; e < N_EDGES;
       e += (long)gridDim.x * blockDim.x)
    atomicAdd(&counts[ei[N_EDGES + e]], 1);
}

__global__ __launch_bounds__(1024) void scan_k(const int* __restrict__ counts,
                                               int* __restrict__ offs, int* __restrict__ cursor) {
  __shared__ int sd[1024];
  int tid = threadIdx.x;
  const int CH = (N_NODES + 1023) / 1024;
  int i0 = tid * CH;
  int s = 0;
  for (int i = 0; i < CH; ++i) { int idx = i0 + i; if (idx < N_NODES) s += counts[idx]; }
  sd[tid] = s; __syncthreads();
  for (int off = 1; off < 1024; off <<= 1) {
    int v = (tid >= off) ? sd[tid - off] : 0;
    __syncthreads();
    sd[tid] += v;
    __syncthreads();
  }
  int run = sd[tid] - s;
  for (int i = 0; i < CH; ++i) {
    int idx = i0 + i;
    if (idx < N_NODES) { offs[idx] = run; cursor[idx] = run; run += counts[idx]; }
  }
  if (tid == 1023) offs[N_NODES] = run;
}

__global__ void scatter_k(const int* __restrict__ ei, int* __restrict__ cursor,
                          int* __restrict__ elist) {
  for (long e = blockIdx.x * (long)blockDim.x + threadIdx.x; e < N_EDGES;
       e += (long)gridDim.x * blockDim.x) {
    int d = ei[N_EDGES + e];
    int pos = atomicAdd(&cursor[d], 1);
    elist[pos] = (int)e;
  }
}

// ---------------- attention edge/softmax kernels ----------------
__global__ __launch_bounds__(256) void edge_alpha(const int* __restrict__ ei,
    const f16* __restrict__ Qn, const f16* __restrict__ Kn, const f16* __restrict__ emat,
    float* __restrict__ exo) {
  int lane = threadIdx.x & 63;
  long wid = (blockIdx.x * 256L + threadIdx.x) >> 6;
  long nw = (gridDim.x * 256L) >> 6;
  for (long e = wid; e < N_EDGES; e += nw) {
    int s = ei[e], d = ei[N_EDGES + e];
    f16x2 q2 = *(const f16x2*)(Qn + (long)d * DIM + 2 * lane);
    f16x2 k2 = *(const f16x2*)(Kn + (long)s * DIM + 2 * lane);
    f16x2 e2 = *(const f16x2*)(emat + e * DIM + 2 * lane);
    float p = (float)q2[0] * ((float)k2[0] + (float)e2[0]) +
              (float)q2[1] * ((float)k2[1] + (float)e2[1]);
    p += __shfl_xor(p, 1);
    p += __shfl_xor(p, 2);
    p += __shfl_xor(p, 4);
    float ex = __expf(p * 0.25f);
    if ((lane & 7) == 0) exo[e * 8 + (lane >> 3)] = ex;
  }
}

// per dst node: out = sum(ex*(e+V[src]))/sum(ex); index chain prefetched 1 ahead
__global__ __launch_bounds__(256) void attn_gather(const int* __restrict__ ei,
    const int* __restrict__ offs, const int* __restrict__ elist, const float* __restrict__ exv,
    const f16* __restrict__ emat, const f16* __restrict__ Vn, float* __restrict__ outp) {
  int n = blockIdx.x * 4 + (threadIdx.x >> 6);
  if (n >= N_NODES) return;
  int lane = threadIdx.x & 63;
  int h = lane >> 3;
  int rs = offs[n], re = offs[n + 1];
  float a0 = 0.f, a1 = 0.f, den = 0.f;
  int eid_n = 0, s_n = 0;
  if (rs < re) { eid_n = elist[rs]; s_n = ei[eid_n]; }
  for (int i = rs; i < re; ++i) {
    int eid = eid_n, s = s_n;
    if (i + 1 < re) { eid_n = elist[i + 1]; s_n = ei[eid_n]; }
    float exh = exv[(long)eid * 8 + h];
    f16x2 e2 = *(const f16x2*)(emat + (long)eid * DIM + 2 * lane);
    f16x2 v2 = *(const f16x2*)(Vn + (long)s * DIM + 2 * lane);
    a0 += exh * ((float)e2[0] + (float)v2[0]);
    a1 += exh * ((float)e2[1] + (float)v2[1]);
    den += exh;
  }
  float inv = 1.f / (den + 1e-16f);
  float2 o; o.x = a0 * inv; o.y = a1 * inv;
  *(float2*)(outp + (long)n * DIM + 2 * lane) = o;
}

// out = base + LN(xa [+ xb]) * g + b
__global__ __launch_bounds__(256) void post_ln(const float* __restrict__ xa,
    const float* __restrict__ xb, const float* __restrict__ base,
    const float* __restrict__ g, const float* __restrict__ b, float* __restrict__ outp) {
  int n = blockIdx.x * 4 + (threadIdx.x >> 6);
  if (n >= N_NODES) return;
  int lane = threadIdx.x & 63;
  float2 x = *(const float2*)(xa + (long)n * DIM + 2 * lane);
  if (xb) {
    float2 y = *(const float2*)(xb + (long)n * DIM + 2 * lane);
    x.x += y.x; x.y += y.y;
  }
  float sm = x.x + x.y;
  for (int m = 1; m < 64; m <<= 1) sm += __shfl_xor(sm, m);
  float mu = sm * (1.f / 128.f);
  float dx = x.x - mu, dy = x.y - mu;
  float ss = dx * dx + dy * dy;
  for (int m = 1; m < 64; m <<= 1) ss += __shfl_xor(ss, m);
  float r = rsqrtf(ss * (1.f / 128.f) + 1e-5f);
  float2 gg = *(const float2*)(g + 2 * lane);
  float2 bb = *(const float2*)(b + 2 * lane);
  float2 bs = *(const float2*)(base + (long)n * DIM + 2 * lane);
  float2 o;
  o.x = bs.x + dx * r * gg.x + bb.x;
  o.y = bs.y + dy * r * gg.y + bb.y;
  *(float2*)(outp + (long)n * DIM + 2 * lane) = o;
}

// ---------------- launch ----------------
extern "C" void kernel_launch(void* const* d_in, const int* in_sizes, int n_in,
                              void* d_out, int out_size, void* d_ws, size_t ws_size,
                              hipStream_t stream) {
  (void)in_sizes; (void)n_in; (void)out_size; (void)ws_size;
  const int*   ei  = (const int*)d_in[0];
  const float* x0  = (const float*)d_in[1];
  const float* ea  = (const float*)d_in[2];
  const float* Wq  = (const float*)d_in[3];  const float* bq = (const float*)d_in[4];
  const float* Wk  = (const float*)d_in[5];  const float* bk = (const float*)d_in[6];
  const float* Wv  = (const float*)d_in[7];  const float* bv = (const float*)d_in[8];
  const float* We  = (const float*)d_in[9];  const float* be = (const float*)d_in[10];
  const float* Wsk = (const float*)d_in[11]; const float* bsk = (const float*)d_in[12];
  const float* W1  = (const float*)d_in[13]; const float* b1 = (const float*)d_in[14];
  const float* W2  = (const float*)d_in[15]; const float* b2 = (const float*)d_in[16];
  const float* g1  = (const float*)d_in[17]; const float* lb1 = (const float*)d_in[18];
  const float* g2  = (const float*)d_in[19]; const float* lb2 = (const float*)d_in[20];

  char* ws = (char*)d_ws;
  f16*   Qn     = (f16*)(ws + 0);
  f16*   Kn     = (f16*)(ws + 12800000L);
  f16*   Vn     = (f16*)(ws + 25600000L);
  float* Skip   = (float*)(ws + 38400000L);
  float* exv    = (float*)(ws + 64000000L);
  int*   offs   = (int*)(ws + 89600000L);
  f16*   WhAll  = (f16*)(ws + 89800192L);    // 229376 B; overlays cursor+counts (dead after CSR)
  int*   cursor = (int*)(ws + 89800192L);
  int*   counts = (int*)(ws + 90030592L);
  int*   elist  = (int*)(ws + 90230784L);
  f16*   emat   = (f16*)(ws + 93430784L);
  float* node1  = (float*)(ws + 298230784L);
  float* hid    = (float*)(ws + 38400000L);  // reuse Skip (dead after post_ln1)
  float* h2     = (float*)(ws + 0);          // reuse Qn/Kn (dead after edge_alpha)
  float* attn   = (float*)d_out;             // staging; overwritten by final post_ln

  hipMemsetAsync(counts, 0, N_NODES * sizeof(int), stream);
  hist_k<<<1024, 256, 0, stream>>>(ei, counts);
  scan_k<<<1, 1024, 0, stream>>>(counts, offs, cursor);
  scatter_k<<<1024, 256, 0, stream>>>(ei, cursor, elist);
  convert7<<<112, 1024, 0, stream>>>(Wq, Wk, Wv, Wsk, We, W1, W2, WhAll);

  node4_v3<<<1024, 256, 0, stream>>>(x0, WhAll, bq, bk, bv, bsk, Qn, Kn, Vn, Skip);
  gemm_v3<1, 0><<<2048, 256, 0, stream>>>(ea, (long)N_EDGES, N_EDGES / 64,
                                          WhAll + 4 * 16384, be, emat);
  edge_alpha<<<4096, 256, 0, stream>>>(ei, Qn, Kn, emat, exv);
  attn_gather<<<12500, 256, 0, stream>>>(ei, offs, elist, exv, emat, Vn, attn);
  post_ln<<<12500, 256, 0, stream>>>(attn, Skip, x0, g1, lb1, node1);
  gemm_v3<0, 1><<<NODE_TILES, 256, 0, stream>>>(node1, (long)N_NODES, NODE_TILES,
                                                WhAll + 5 * 16384, b1, hid);
  gemm_v3<0, 0><<<NODE_TILES, 256, 0, stream>>>(hid, (long)N_NODES, NODE_TILES,
                                                WhAll + 6 * 16384, b2, h2);
  post_ln<<<12500, 256, 0, stream>>>(h2, nullptr, node1, g2, lb2, (float*)d_out);
}

// Round 5
// 692.308 us; speedup vs baseline: 1.3013x; 1.1674x over previous
//
#include <hip/hip_runtime.h>
#include <hip/hip_fp16.h>

#define N_NODES 50000
#define N_EDGES 800000
#define DIM 128
#define NODE_TILES 782   // ceil(50000/64)

typedef _Float16 f16;
typedef _Float16 f16x2 __attribute__((ext_vector_type(2)));
typedef _Float16 f16x4 __attribute__((ext_vector_type(4)));
typedef _Float16 f16x8 __attribute__((ext_vector_type(8)));
typedef float    f32x16 __attribute__((ext_vector_type(16)));

__device__ __forceinline__ void sfence() { __builtin_amdgcn_sched_barrier(0); }

// ---------------- shared GEMM pieces ----------------
__device__ __forceinline__ void load_wfrag(const f16* __restrict__ Wh, int ch, int l31, int g,
                                           f16x8 bf[2][8]) {
#pragma unroll
  for (int c = 0; c < 2; ++c)
#pragma unroll
    for (int ks = 0; ks < 8; ++ks)
      bf[c][ks] = *(const f16x8*)(Wh + ((ch * 64 + c * 32 + l31) << 7) + 16 * ks + 8 * g);
}

template <int HALF_OUT, int SILU>
__device__ __forceinline__ void gemm_store(f32x16 acc[2], long M, const float* __restrict__ Bv,
                                           void* __restrict__ OUT,
                                           long tile0, int rc, int ch, int l31, int g) {
#pragma unroll
  for (int c = 0; c < 2; ++c) {
    int col = ch * 64 + c * 32 + l31;
    float bv = Bv[col];
#pragma unroll
    for (int r = 0; r < 16; ++r) {
      long gm = tile0 + rc * 32 + ((r & 3) + 8 * (r >> 2) + 4 * g);
      if (gm < M) {
        float v = acc[c][r] + bv;
        if (SILU) v = v / (1.0f + __expf(-v));
        if (HALF_OUT) ((f16*)OUT)[gm * DIM + col] = (f16)v;
        else          ((float*)OUT)[gm * DIM + col] = v;
      }
    }
  }
}

// ---------------- GEMM v4: coalesced LDS-staged, double-buffered ----------------
// Tile: 64 rows x 128 cols. LDS f16 tile, row = 256B = 16 slots of 16B,
// swizzle: slot16' = slot16 ^ (row & 15). Stage converts f32->f16.
__device__ __forceinline__ void stage_issue(const float* __restrict__ X, long M, long base,
                                            int tid, float4 sv[8]) {
#pragma unroll
  for (int kk = 0; kk < 8; ++kk) {
    int i = tid + kk * 256;            // [0, 2048): 64 rows x 32 slots of 16B(f32)
    long row = base + (i >> 5);
    long gr = row < M ? row : (M - 1);
    sv[kk] = *(const float4*)(X + gr * DIM + (i & 31) * 4);   // fully coalesced
  }
}

__device__ __forceinline__ void stage_write(const float4 sv[8], int tid, f16* __restrict__ lds) {
#pragma unroll
  for (int kk = 0; kk < 8; ++kk) {
    int i = tid + kk * 256;
    int r = i >> 5, s8 = i & 31;
    f16x4 h;
    h[0] = (f16)sv[kk].x; h[1] = (f16)sv[kk].y; h[2] = (f16)sv[kk].z; h[3] = (f16)sv[kk].w;
    // f16 units: row*128 + ((s8>>1)^(r&15))*8 + (s8&1)*4
    *(f16x4*)(lds + r * 128 + (((s8 >> 1) ^ (r & 15)) << 3) + ((s8 & 1) << 2)) = h;
  }
}

template <int HALF_OUT, int SILU>
__global__ __launch_bounds__(256) void gemm_v4(const float* __restrict__ X, long M, int ntiles,
                                               const f16* __restrict__ Wh,
                                               const float* __restrict__ Bv,
                                               void* __restrict__ OUT) {
  __shared__ f16 lbuf[2][64 * 128];   // 2 x 16 KB
  int tid = threadIdx.x;
  int lane = tid & 63, w = tid >> 6;
  int rc = w >> 1, ch = w & 1, l31 = lane & 31, g = lane >> 5;
  int t0 = blockIdx.x;
  if (t0 >= ntiles) return;

  f16x8 bf[2][8];
  load_wfrag(Wh, ch, l31, g, bf);

  float4 sv[8];
  stage_issue(X, M, (long)t0 * 64, tid, sv);
  stage_write(sv, tid, lbuf[0]);
  __syncthreads();

  int cur = 0;
  int lr = rc * 32 + l31;             // this wave-lane's LDS row
  for (int t = t0; t < ntiles; t += gridDim.x) {
    int tn = t + gridDim.x;
    if (tn < ntiles) stage_issue(X, M, (long)tn * 64, tid, sv);
    sfence();                          // pin load cluster above compute

    f32x16 acc[2];
#pragma unroll
    for (int c = 0; c < 2; ++c)
#pragma unroll
      for (int k = 0; k < 16; ++k) acc[c][k] = 0.0f;
    const f16* A = lbuf[cur];
#pragma unroll
    for (int ks = 0; ks < 8; ++ks) {
      f16x8 a = *(const f16x8*)(A + lr * 128 + (((2 * ks + g) ^ (lr & 15)) << 3));
      acc[0] = __builtin_amdgcn_mfma_f32_32x32x16_f16(a, bf[0][ks], acc[0], 0, 0, 0);
      acc[1] = __builtin_amdgcn_mfma_f32_32x32x16_f16(a, bf[1][ks], acc[1], 0, 0, 0);
    }
    gemm_store<HALF_OUT, SILU>(acc, M, Bv, OUT, (long)t * 64, rc, ch, l31, g);

    if (tn < ntiles) {
      asm volatile("s_waitcnt vmcnt(0)" ::: "memory");   // sv arrived (hid under compute)
      stage_write(sv, tid, lbuf[cur ^ 1]);
    }
    __syncthreads();                   // writes visible; all reads of lbuf[cur] done
    cur ^= 1;
  }
}

// ---------------- GEMM v3 (register-direct) for small node GEMMs ----------------
__device__ __forceinline__ void issue_aloads(const float* __restrict__ xp,
                                             float4 av0[8], float4 av1[8]) {
#pragma unroll
  for (int ks = 0; ks < 8; ++ks) {
    av0[ks] = *(const float4*)(xp + 16 * ks);
    av1[ks] = *(const float4*)(xp + 16 * ks + 4);
  }
}

__device__ __forceinline__ void compute_tile(const float4 av0[8], const float4 av1[8],
                                             const f16x8 bf[2][8], f32x16 acc[2]) {
#pragma unroll
  for (int c = 0; c < 2; ++c)
#pragma unroll
    for (int k = 0; k < 16; ++k) acc[c][k] = 0.0f;
#pragma unroll
  for (int ks = 0; ks < 8; ++ks) {
    f16x8 a;
    a[0] = (f16)av0[ks].x; a[1] = (f16)av0[ks].y; a[2] = (f16)av0[ks].z; a[3] = (f16)av0[ks].w;
    a[4] = (f16)av1[ks].x; a[5] = (f16)av1[ks].y; a[6] = (f16)av1[ks].z; a[7] = (f16)av1[ks].w;
    acc[0] = __builtin_amdgcn_mfma_f32_32x32x16_f16(a, bf[0][ks], acc[0], 0, 0, 0);
    acc[1] = __builtin_amdgcn_mfma_f32_32x32x16_f16(a, bf[1][ks], acc[1], 0, 0, 0);
  }
}

template <int HALF_OUT, int SILU>
__global__ __launch_bounds__(256) void gemm_v3(const float* __restrict__ X, long M, int ntiles,
                                               const f16* __restrict__ Wh,
                                               const float* __restrict__ Bv,
                                               void* __restrict__ OUT) {
  int lane = threadIdx.x & 63, w = threadIdx.x >> 6;
  int rc = w >> 1, ch = w & 1, l31 = lane & 31, g = lane >> 5;
  f16x8 bf[2][8];
  load_wfrag(Wh, ch, l31, g, bf);
  for (long t = blockIdx.x; t < ntiles; t += gridDim.x) {
    long tile0 = t * 64;
    long row = tile0 + rc * 32 + l31;
    long gr = row < M ? row : (M - 1);
    const float* xp = X + gr * DIM + 8 * g;
    float4 av0[8], av1[8];
    issue_aloads(xp, av0, av1);
    sfence();
    f32x16 acc[2];
    compute_tile(av0, av1, bf, acc);
    gemm_store<HALF_OUT, SILU>(acc, M, Bv, OUT, tile0, rc, ch, l31, g);
    sfence();
  }
}

// Q/K/V/skip fused (register-direct; X is L3-resident)
__global__ __launch_bounds__(256) void node4_v3(const float* __restrict__ X,
    const f16* __restrict__ WhAll,
    const float* __restrict__ bq, const float* __restrict__ bk,
    const float* __restrict__ bv_, const float* __restrict__ bs,
    f16* __restrict__ Q, f16* __restrict__ K, f16* __restrict__ V, float* __restrict__ S) {
  int lane = threadIdx.x & 63, w = threadIdx.x >> 6;
  int rc = w >> 1, ch = w & 1, l31 = lane & 31, g = lane >> 5;
  for (int t = blockIdx.x; t < 4 * NODE_TILES; t += gridDim.x) {
    int mat = t / NODE_TILES;
    long tile0 = (long)(t - mat * NODE_TILES) * 64;
    long row = tile0 + rc * 32 + l31;
    long gr = row < N_NODES ? row : (N_NODES - 1);
    const float* xp = X + gr * DIM + 8 * g;
    float4 av0[8], av1[8];
    f16x8 bf[2][8];
    issue_aloads(xp, av0, av1);
    load_wfrag(WhAll + mat * 16384, ch, l31, g, bf);
    sfence();
    f32x16 acc[2];
    compute_tile(av0, av1, bf, acc);
    if (mat == 0)      gemm_store<1, 0>(acc, N_NODES, bq, Q, tile0, rc, ch, l31, g);
    else if (mat == 1) gemm_store<1, 0>(acc, N_NODES, bk, K, tile0, rc, ch, l31, g);
    else if (mat == 2) gemm_store<1, 0>(acc, N_NODES, bv_, V, tile0, rc, ch, l31, g);
    else               gemm_store<0, 0>(acc, N_NODES, bs, S, tile0, rc, ch, l31, g);
    sfence();
  }
}

// convert all 7 weight matrices f32 -> f16
__global__ void convert7(const float* __restrict__ a0, const float* __restrict__ a1,
                         const float* __restrict__ a2, const float* __restrict__ a3,
                         const float* __restrict__ a4, const float* __restrict__ a5,
                         const float* __restrict__ a6, f16* __restrict__ dst) {
  int i = blockIdx.x * blockDim.x + threadIdx.x;
  int mat = i >> 14, el = i & 16383;
  const float* s = (mat == 0) ? a0 : (mat == 1) ? a1 : (mat == 2) ? a2 : (mat == 3) ? a3
                 : (mat == 4) ? a4 : (mat == 5) ? a5 : a6;
  dst[i] = (f16)s[el];
}

// ---------------- CSR build ----------------
__global__ void hist_k(const int* __restrict__ ei, int* __restrict__ counts) {
  for (long e = blockIdx.x * (long)blockDim.x + threadIdx.x; e < N_EDGES;
       e += (long)gridDim.x * blockDim.x)
    atomicAdd(&counts[ei[N_EDGES + e]], 1);
}

__global__ __launch_bounds__(1024) void scan_k(const int* __restrict__ counts,
                                               int* __restrict__ offs, int* __restrict__ cursor) {
  __shared__ int sd[1024];
  int tid = threadIdx.x;
  const int CH = (N_NODES + 1023) / 1024;
  int i0 = tid * CH;
  int s = 0;
  for (int i = 0; i < CH; ++i) { int idx = i0 + i; if (idx < N_NODES) s += counts[idx]; }
  sd[tid] = s; __syncthreads();
  for (int off = 1; off < 1024; off <<= 1) {
    int v = (tid >= off) ? sd[tid - off] : 0;
    __syncthreads();
    sd[tid] += v;
    __syncthreads();
  }
  int run = sd[tid] - s;
  for (int i = 0; i < CH; ++i) {
    int idx = i0 + i;
    if (idx < N_NODES) { offs[idx] = run; cursor[idx] = run; run += counts[idx]; }
  }
  if (tid == 1023) offs[N_NODES] = run;
}

__global__ void scatter_k(const int* __restrict__ ei, int* __restrict__ cursor,
                          int* __restrict__ elist) {
  for (long e = blockIdx.x * (long)blockDim.x + threadIdx.x; e < N_EDGES;
       e += (long)gridDim.x * blockDim.x) {
    int d = ei[N_EDGES + e];
    int pos = atomicAdd(&cursor[d], 1);
    elist[pos] = (int)e;
  }
}

// ---------------- fused attention: alpha + online softmax + gather ----------------
// per dst node (1 wave): q loaded once; single pass over edges:
//   p = q·(K[src]+e)/4; ex = exp(p); den += ex; acc += ex*(e+V[src])
__global__ __launch_bounds__(256) void attn_fused(const int* __restrict__ ei,
    const int* __restrict__ offs, const int* __restrict__ elist,
    const f16* __restrict__ emat, const f16* __restrict__ Qn,
    const f16* __restrict__ Kn, const f16* __restrict__ Vn, float* __restrict__ outp) {
  int n = blockIdx.x * 4 + (threadIdx.x >> 6);
  if (n >= N_NODES) return;
  int lane = threadIdx.x & 63;
  float qx, qy;
  { f16x2 q2 = *(const f16x2*)(Qn + (long)n * DIM + 2 * lane); qx = (float)q2[0]; qy = (float)q2[1]; }
  int rs = offs[n], re = offs[n + 1];
  float a0 = 0.f, a1 = 0.f, den = 0.f;
  int eid_n = 0, s_n = 0;
  if (rs < re) { eid_n = elist[rs]; s_n = ei[eid_n]; }
  for (int i = rs; i < re; ++i) {
    int eid = eid_n, s = s_n;
    if (i + 1 < re) { eid_n = elist[i + 1]; s_n = ei[eid_n]; }
    f16x2 e2 = *(const f16x2*)(emat + (long)eid * DIM + 2 * lane);
    f16x2 k2 = *(const f16x2*)(Kn + (long)s * DIM + 2 * lane);
    f16x2 v2 = *(const f16x2*)(Vn + (long)s * DIM + 2 * lane);
    float p = qx * ((float)k2[0] + (float)e2[0]) + qy * ((float)k2[1] + (float)e2[1]);
    p += __shfl_xor(p, 1);
    p += __shfl_xor(p, 2);
    p += __shfl_xor(p, 4);            // 8-lane head group
    float ex = __expf(p * 0.25f);
    den += ex;
    a0 += ex * ((float)e2[0] + (float)v2[0]);
    a1 += ex * ((float)e2[1] + (float)v2[1]);
  }
  float inv = 1.f / (den + 1e-16f);
  float2 o; o.x = a0 * inv; o.y = a1 * inv;
  *(float2*)(outp + (long)n * DIM + 2 * lane) = o;
}

// out = base + LN(xa [+ xb]) * g + b
__global__ __launch_bounds__(256) void post_ln(const float* __restrict__ xa,
    const float* __restrict__ xb, const float* __restrict__ base,
    const float* __restrict__ g, const float* __restrict__ b, float* __restrict__ outp) {
  int n = blockIdx.x * 4 + (threadIdx.x >> 6);
  if (n >= N_NODES) return;
  int lane = threadIdx.x & 63;
  float2 x = *(const float2*)(xa + (long)n * DIM + 2 * lane);
  if (xb) {
    float2 y = *(const float2*)(xb + (long)n * DIM + 2 * lane);
    x.x += y.x; x.y += y.y;
  }
  float sm = x.x + x.y;
  for (int m = 1; m < 64; m <<= 1) sm += __shfl_xor(sm, m);
  float mu = sm * (1.f / 128.f);
  float dx = x.x - mu, dy = x.y - mu;
  float ss = dx * dx + dy * dy;
  for (int m = 1; m < 64; m <<= 1) ss += __shfl_xor(ss, m);
  float r = rsqrtf(ss * (1.f / 128.f) + 1e-5f);
  float2 gg = *(const float2*)(g + 2 * lane);
  float2 bb = *(const float2*)(b + 2 * lane);
  float2 bs = *(const float2*)(base + (long)n * DIM + 2 * lane);
  float2 o;
  o.x = bs.x + dx * r * gg.x + bb.x;
  o.y = bs.y + dy * r * gg.y + bb.y;
  *(float2*)(outp + (long)n * DIM + 2 * lane) = o;
}

// ---------------- launch ----------------
extern "C" void kernel_launch(void* const* d_in, const int* in_sizes, int n_in,
                              void* d_out, int out_size, void* d_ws, size_t ws_size,
                              hipStream_t stream) {
  (void)in_sizes; (void)n_in; (void)out_size; (void)ws_size;
  const int*   ei  = (const int*)d_in[0];
  const float* x0  = (const float*)d_in[1];
  const float* ea  = (const float*)d_in[2];
  const float* Wq  = (const float*)d_in[3];  const float* bq = (const float*)d_in[4];
  const float* Wk  = (const float*)d_in[5];  const float* bk = (const float*)d_in[6];
  const float* Wv  = (const float*)d_in[7];  const float* bv = (const float*)d_in[8];
  const float* We  = (const float*)d_in[9];  const float* be = (const float*)d_in[10];
  const float* Wsk = (const float*)d_in[11]; const float* bsk = (const float*)d_in[12];
  const float* W1  = (const float*)d_in[13]; const float* b1 = (const float*)d_in[14];
  const float* W2  = (const float*)d_in[15]; const float* b2 = (const float*)d_in[16];
  const float* g1  = (const float*)d_in[17]; const float* lb1 = (const float*)d_in[18];
  const float* g2  = (const float*)d_in[19]; const float* lb2 = (const float*)d_in[20];

  char* ws = (char*)d_ws;
  f16*   Qn     = (f16*)(ws + 0);
  f16*   Kn     = (f16*)(ws + 12800000L);
  f16*   Vn     = (f16*)(ws + 25600000L);
  float* Skip   = (float*)(ws + 38400000L);
  int*   offs   = (int*)(ws + 64000000L);      // 200,004 B (pad to 200,192)
  f16*   WhAll  = (f16*)(ws + 64200192L);      // 229,376 B; overlays cursor (dead after CSR)
  int*   cursor = (int*)(ws + 64200192L);
  int*   counts = (int*)(ws + 64429568L);      // 200,000 B
  int*   elist  = (int*)(ws + 64629760L);      // 3,200,000 B
  f16*   emat   = (f16*)(ws + 67829760L);      // 204,800,000 B
  float* node1  = (float*)(ws + 272629760L);   // 25,600,000 B
  float* hid    = (float*)(ws + 38400000L);    // reuse Skip (dead after post_ln1)
  float* h2     = (float*)(ws + 0);            // reuse Qn/Kn (dead after attn_fused)
  float* attn   = (float*)d_out;               // staging; overwritten by final post_ln

  hipMemsetAsync(counts, 0, N_NODES * sizeof(int), stream);
  hist_k<<<1024, 256, 0, stream>>>(ei, counts);
  scan_k<<<1, 1024, 0, stream>>>(counts, offs, cursor);
  scatter_k<<<1024, 256, 0, stream>>>(ei, cursor, elist);
  convert7<<<112, 1024, 0, stream>>>(Wq, Wk, Wv, Wsk, We, W1, W2, WhAll);

  node4_v3<<<1024, 256, 0, stream>>>(x0, WhAll, bq, bk, bv, bsk, Qn, Kn, Vn, Skip);
  gemm_v4<1, 0><<<2048, 256, 0, stream>>>(ea, (long)N_EDGES, N_EDGES / 64,
                                          WhAll + 4 * 16384, be, emat);
  attn_fused<<<12500, 256, 0, stream>>>(ei, offs, elist, emat, Qn, Kn, Vn, attn);
  post_ln<<<12500, 256, 0, stream>>>(attn, Skip, x0, g1, lb1, node1);
  gemm_v3<0, 1><<<NODE_TILES, 256, 0, stream>>>(node1, (long)N_NODES, NODE_TILES,
                                                WhAll + 5 * 16384, b1, hid);
  gemm_v3<0, 0><<<NODE_TILES, 256, 0, stream>>>(hid, (long)N_NODES, NODE_TILES,
                                                WhAll + 6 * 16384, b2, h2);
  post_ln<<<12500, 256, 0, stream>>>(h2, nullptr, node1, g2, lb2, (float*)d_out);
}

// Round 7
// 655.680 us; speedup vs baseline: 1.3740x; 1.0559x over previous
//
#include <hip/hip_runtime.h>
#include <hip/hip_fp16.h>

#define N_NODES 50000
#define N_EDGES 800000
#define DIM 128
#define NODE_TILES 782   // ceil(50000/64)
#define EDGE_TILES 12500 // 800000/64

typedef _Float16 f16;
typedef _Float16 f16x2 __attribute__((ext_vector_type(2)));
typedef _Float16 f16x4 __attribute__((ext_vector_type(4)));
typedef _Float16 f16x8 __attribute__((ext_vector_type(8)));
typedef float    f32x16 __attribute__((ext_vector_type(16)));

__device__ __forceinline__ void sfence() { __builtin_amdgcn_sched_barrier(0); }

// ---------------- shared GEMM pieces ----------------
__device__ __forceinline__ void load_wfrag(const f16* __restrict__ Wh, int ch, int l31, int g,
                                           f16x8 bf[2][8]) {
#pragma unroll
  for (int c = 0; c < 2; ++c)
#pragma unroll
    for (int ks = 0; ks < 8; ++ks)
      bf[c][ks] = *(const f16x8*)(Wh + ((ch * 64 + c * 32 + l31) << 7) + 16 * ks + 8 * g);
}

template <int HALF_OUT, int SILU>
__device__ __forceinline__ void gemm_store(f32x16 acc[2], long M, const float* __restrict__ Bv,
                                           void* __restrict__ OUT,
                                           long tile0, int rc, int ch, int l31, int g) {
#pragma unroll
  for (int c = 0; c < 2; ++c) {
    int col = ch * 64 + c * 32 + l31;
    float bv = Bv[col];
#pragma unroll
    for (int r = 0; r < 16; ++r) {
      long gm = tile0 + rc * 32 + ((r & 3) + 8 * (r >> 2) + 4 * g);
      if (gm < M) {
        float v = acc[c][r] + bv;
        if (SILU) v = v / (1.0f + __expf(-v));
        if (HALF_OUT) ((f16*)OUT)[gm * DIM + col] = (f16)v;
        else          ((float*)OUT)[gm * DIM + col] = v;
      }
    }
  }
}

// ---------------- v4 staging: coalesced, f32->f16, XOR-swizzled LDS ----------------
__device__ __forceinline__ void stage_issue(const float* __restrict__ X, long M, long base,
                                            int tid, float4 sv[8]) {
#pragma unroll
  for (int kk = 0; kk < 8; ++kk) {
    int i = tid + kk * 256;            // [0, 2048): 64 rows x 32 slots of 16B(f32)
    long row = base + (i >> 5);
    long gr = row < M ? row : (M - 1);
    sv[kk] = *(const float4*)(X + gr * DIM + (i & 31) * 4);   // fully coalesced
  }
}

// gather variant: tile rows are elist[base..base+64) (dst-sorted edge order)
__device__ __forceinline__ void stage_issue_g(const float* __restrict__ X,
                                              const int* __restrict__ elist, long base,
                                              int tid, float4 sv[8]) {
#pragma unroll
  for (int kk = 0; kk < 8; ++kk) {
    int i = tid + kk * 256;
    int eid = elist[base + (i >> 5)];      // L2-hot, broadcast within 32-thread group
    sv[kk] = *(const float4*)(X + (long)eid * DIM + (i & 31) * 4);  // full 512B row segs
  }
}

__device__ __forceinline__ void stage_write(const float4 sv[8], int tid, f16* __restrict__ lds) {
#pragma unroll
  for (int kk = 0; kk < 8; ++kk) {
    int i = tid + kk * 256;
    int r = i >> 5, s8 = i & 31;
    f16x4 h;
    h[0] = (f16)sv[kk].x; h[1] = (f16)sv[kk].y; h[2] = (f16)sv[kk].z; h[3] = (f16)sv[kk].w;
    *(f16x4*)(lds + r * 128 + (((s8 >> 1) ^ (r & 15)) << 3) + ((s8 & 1) << 2)) = h;
  }
}

// gemm over LDS tile
__device__ __forceinline__ void mfma_lds_g(const f16* __restrict__ A, int lr, int g,
                                           const f16x8 bf[2][8], f32x16 acc[2]) {
#pragma unroll
  for (int c = 0; c < 2; ++c)
#pragma unroll
    for (int k = 0; k < 16; ++k) acc[c][k] = 0.0f;
#pragma unroll
  for (int ks = 0; ks < 8; ++ks) {
    f16x8 a = *(const f16x8*)(A + lr * 128 + (((2 * ks + g) ^ (lr & 15)) << 3));
    acc[0] = __builtin_amdgcn_mfma_f32_32x32x16_f16(a, bf[0][ks], acc[0], 0, 0, 0);
    acc[1] = __builtin_amdgcn_mfma_f32_32x32x16_f16(a, bf[1][ks], acc[1], 0, 0, 0);
  }
}

// ---------------- GEMM v4 (sequential rows), double-buffered ----------------
template <int HALF_OUT, int SILU>
__global__ __launch_bounds__(256) void gemm_v4(const float* __restrict__ X, long M, int ntiles,
                                               const f16* __restrict__ Wh,
                                               const float* __restrict__ Bv,
                                               void* __restrict__ OUT) {
  __shared__ f16 lbuf[2][64 * 128];
  int tid = threadIdx.x;
  int lane = tid & 63, w = tid >> 6;
  int rc = w >> 1, ch = w & 1, l31 = lane & 31, g = lane >> 5;
  int t0 = blockIdx.x;
  if (t0 >= ntiles) return;
  f16x8 bf[2][8];
  load_wfrag(Wh, ch, l31, g, bf);
  float4 sv[8];
  stage_issue(X, M, (long)t0 * 64, tid, sv);
  stage_write(sv, tid, lbuf[0]);
  __syncthreads();
  int cur = 0;
  int lr = rc * 32 + l31;
  for (int t = t0; t < ntiles; t += gridDim.x) {
    int tn = t + gridDim.x;
    if (tn < ntiles) stage_issue(X, M, (long)tn * 64, tid, sv);
    sfence();
    f32x16 acc[2];
    mfma_lds_g(lbuf[cur], lr, g, bf, acc);
    gemm_store<HALF_OUT, SILU>(acc, M, Bv, OUT, (long)t * 64, rc, ch, l31, g);
    if (tn < ntiles) {
      asm volatile("s_waitcnt vmcnt(0)" ::: "memory");
      stage_write(sv, tid, lbuf[cur ^ 1]);
    }
    __syncthreads();
    cur ^= 1;
  }
}

// ---------------- GEMM v4g (rows gathered via elist), double-buffered ----------------
template <int HALF_OUT>
__global__ __launch_bounds__(256) void gemm_v4g(const float* __restrict__ X, long M, int ntiles,
                                                const int* __restrict__ elist,
                                                const f16* __restrict__ Wh,
                                                const float* __restrict__ Bv,
                                                void* __restrict__ OUT) {
  __shared__ f16 lbuf[2][64 * 128];
  int tid = threadIdx.x;
  int lane = tid & 63, w = tid >> 6;
  int rc = w >> 1, ch = w & 1, l31 = lane & 31, g = lane >> 5;
  int t0 = blockIdx.x;
  if (t0 >= ntiles) return;
  f16x8 bf[2][8];
  load_wfrag(Wh, ch, l31, g, bf);
  float4 sv[8];
  stage_issue_g(X, elist, (long)t0 * 64, tid, sv);
  stage_write(sv, tid, lbuf[0]);
  __syncthreads();
  int cur = 0;
  int lr = rc * 32 + l31;
  for (int t = t0; t < ntiles; t += gridDim.x) {
    int tn = t + gridDim.x;
    if (tn < ntiles) stage_issue_g(X, elist, (long)tn * 64, tid, sv);
    sfence();
    f32x16 acc[2];
    mfma_lds_g(lbuf[cur], lr, g, bf, acc);
    gemm_store<HALF_OUT, 0>(acc, M, Bv, OUT, (long)t * 64, rc, ch, l31, g);
    if (tn < ntiles) {
      asm volatile("s_waitcnt vmcnt(0)" ::: "memory");
      stage_write(sv, tid, lbuf[cur ^ 1]);
    }
    __syncthreads();
    cur ^= 1;
  }
}

// ---------------- node4 v4: X-tile staged once, 4 weight mats ----------------
__global__ __launch_bounds__(256) void node4_v4(const float* __restrict__ X,
    const f16* __restrict__ WhAll,
    const float* __restrict__ bq, const float* __restrict__ bk,
    const float* __restrict__ bv_, const float* __restrict__ bs,
    f16* __restrict__ Q, f16* __restrict__ K, f16* __restrict__ V, float* __restrict__ S) {
  __shared__ f16 xs[64 * 128];
  int tid = threadIdx.x;
  int lane = tid & 63, w = tid >> 6;
  int rc = w >> 1, ch = w & 1, l31 = lane & 31, g = lane >> 5;
  int t = blockIdx.x;
  if (t >= NODE_TILES) return;
  long tile0 = (long)t * 64;
  float4 sv[8];
  stage_issue(X, N_NODES, tile0, tid, sv);
  stage_write(sv, tid, xs);
  __syncthreads();
  int lr = rc * 32 + l31;
#pragma unroll 1
  for (int mat = 0; mat < 4; ++mat) {
    f16x8 bf[2][8];
    load_wfrag(WhAll + mat * 16384, ch, l31, g, bf);
    f32x16 acc[2];
    mfma_lds_g(xs, lr, g, bf, acc);
    if (mat == 0)      gemm_store<1, 0>(acc, N_NODES, bq, Q, tile0, rc, ch, l31, g);
    else if (mat == 1) gemm_store<1, 0>(acc, N_NODES, bk, K, tile0, rc, ch, l31, g);
    else if (mat == 2) gemm_store<1, 0>(acc, N_NODES, bv_, V, tile0, rc, ch, l31, g);
    else               gemm_store<0, 0>(acc, N_NODES, bs, S, tile0, rc, ch, l31, g);
  }
}

// convert all 7 weight matrices f32 -> f16
__global__ void convert7(const float* __restrict__ a0, const float* __restrict__ a1,
                         const float* __restrict__ a2, const float* __restrict__ a3,
                         const float* __restrict__ a4, const float* __restrict__ a5,
                         const float* __restrict__ a6, f16* __restrict__ dst) {
  int i = blockIdx.x * blockDim.x + threadIdx.x;
  int mat = i >> 14, el = i & 16383;
  const float* s = (mat == 0) ? a0 : (mat == 1) ? a1 : (mat == 2) ? a2 : (mat == 3) ? a3
                 : (mat == 4) ? a4 : (mat == 5) ? a5 : a6;
  dst[i] = (f16)s[el];
}

// ---------------- CSR build ----------------
__global__ void hist_k(const int* __restrict__ ei, int* __restrict__ counts) {
  for (long e = blockIdx.x * (long)blockDim.x + threadIdx.x; e < N_EDGES;
       e += (long)gridDim.x * blockDim.x)
    atomicAdd(&counts[ei[N_EDGES + e]], 1);
}

__global__ __launch_bounds__(1024) void scan_k(const int* __restrict__ counts,
                                               int* __restrict__ offs, int* __restrict__ cursor) {
  __shared__ int sd[1024];
  int tid = threadIdx.x;
  const int CH = (N_NODES + 1023) / 1024;
  int i0 = tid * CH;
  int s = 0;
  for (int i = 0; i < CH; ++i) { int idx = i0 + i; if (idx < N_NODES) s += counts[idx]; }
  sd[tid] = s; __syncthreads();
  for (int off = 1; off < 1024; off <<= 1) {
    int v = (tid >= off) ? sd[tid - off] : 0;
    __syncthreads();
    sd[tid] += v;
    __syncthreads();
  }
  int run = sd[tid] - s;
  for (int i = 0; i < CH; ++i) {
    int idx = i0 + i;
    if (idx < N_NODES) { offs[idx] = run; cursor[idx] = run; run += counts[idx]; }
  }
  if (tid == 1023) offs[N_NODES] = run;
}

// scatter: elist[pos]=edge id; srcs[pos]=src node of that edge
__global__ void scatter_k(const int* __restrict__ ei, int* __restrict__ cursor,
                          int* __restrict__ elist, int* __restrict__ srcs) {
  for (long e = blockIdx.x * (long)blockDim.x + threadIdx.x; e < N_EDGES;
       e += (long)gridDim.x * blockDim.x) {
    int d = ei[N_EDGES + e];
    int pos = atomicAdd(&cursor[d], 1);
    elist[pos] = (int)e;
    srcs[pos] = ei[e];
  }
}

// ---------------- fused attention over dst-sorted emat ----------------
// emat[pos] (sequential), srcs[pos] (sequential), K/V gathers (L3-hot tables)
__global__ __launch_bounds__(256) void attn_fused(const int* __restrict__ offs,
    const int* __restrict__ srcs, const f16* __restrict__ emat, const f16* __restrict__ Qn,
    const f16* __restrict__ Kn, const f16* __restrict__ Vn, float* __restrict__ outp) {
  int n = blockIdx.x * 4 + (threadIdx.x >> 6);
  if (n >= N_NODES) return;
  int lane = threadIdx.x & 63;
  float qx, qy;
  { f16x2 q2 = *(const f16x2*)(Qn + (long)n * DIM + 2 * lane); qx = (float)q2[0]; qy = (float)q2[1]; }
  int rs = offs[n], re = offs[n + 1];
  float a0 = 0.f, a1 = 0.f, den = 0.f;
  int s_n = (rs < re) ? srcs[rs] : 0;
  for (int i = rs; i < re; ++i) {
    int s = s_n;
    if (i + 1 < re) s_n = srcs[i + 1];
    f16x2 e2 = *(const f16x2*)(emat + (long)i * DIM + 2 * lane);
    f16x2 k2 = *(const f16x2*)(Kn + (long)s * DIM + 2 * lane);
    f16x2 v2 = *(const f16x2*)(Vn + (long)s * DIM + 2 * lane);
    float p = qx * ((float)k2[0] + (float)e2[0]) + qy * ((float)k2[1] + (float)e2[1]);
    p += __shfl_xor(p, 1);
    p += __shfl_xor(p, 2);
    p += __shfl_xor(p, 4);
    float ex = __expf(p * 0.25f);
    den += ex;
    a0 += ex * ((float)e2[0] + (float)v2[0]);
    a1 += ex * ((float)e2[1] + (float)v2[1]);
  }
  float inv = 1.f / (den + 1e-16f);
  float2 o; o.x = a0 * inv; o.y = a1 * inv;
  *(float2*)(outp + (long)n * DIM + 2 * lane) = o;
}

// out = base + LN(xa [+ xb]) * g + b
__global__ __launch_bounds__(256) void post_ln(const float* __restrict__ xa,
    const float* __restrict__ xb, const float* __restrict__ base,
    const float* __restrict__ g, const float* __restrict__ b, float* __restrict__ outp) {
  int n = blockIdx.x * 4 + (threadIdx.x >> 6);
  if (n >= N_NODES) return;
  int lane = threadIdx.x & 63;
  float2 x = *(const float2*)(xa + (long)n * DIM + 2 * lane);
  if (xb) {
    float2 y = *(const float2*)(xb + (long)n * DIM + 2 * lane);
    x.x += y.x; x.y += y.y;
  }
  float sm = x.x + x.y;
  for (int m = 1; m < 64; m <<= 1) sm += __shfl_xor(sm, m);
  float mu = sm * (1.f / 128.f);
  float dx = x.x - mu, dy = x.y - mu;
  float ss = dx * dx + dy * dy;
  for (int m = 1; m < 64; m <<= 1) ss += __shfl_xor(ss, m);
  float r = rsqrtf(ss * (1.f / 128.f) + 1e-5f);
  float2 gg = *(const float2*)(g + 2 * lane);
  float2 bb = *(const float2*)(b + 2 * lane);
  float2 bs = *(const float2*)(base + (long)n * DIM + 2 * lane);
  float2 o;
  o.x = bs.x + dx * r * gg.x + bb.x;
  o.y = bs.y + dy * r * gg.y + bb.y;
  *(float2*)(outp + (long)n * DIM + 2 * lane) = o;
}

// ---------------- launch ----------------
extern "C" void kernel_launch(void* const* d_in, const int* in_sizes, int n_in,
                              void* d_out, int out_size, void* d_ws, size_t ws_size,
                              hipStream_t stream) {
  (void)in_sizes; (void)n_in; (void)out_size; (void)ws_size;
  const int*   ei  = (const int*)d_in[0];
  const float* x0  = (const float*)d_in[1];
  const float* ea  = (const float*)d_in[2];
  const float* Wq  = (const float*)d_in[3];  const float* bq = (const float*)d_in[4];
  const float* Wk  = (const float*)d_in[5];  const float* bk = (const float*)d_in[6];
  const float* Wv  = (const float*)d_in[7];  const float* bv = (const float*)d_in[8];
  const float* We  = (const float*)d_in[9];  const float* be = (const float*)d_in[10];
  const float* Wsk = (const float*)d_in[11]; const float* bsk = (const float*)d_in[12];
  const float* W1  = (const float*)d_in[13]; const float* b1 = (const float*)d_in[14];
  const float* W2  = (const float*)d_in[15]; const float* b2 = (const float*)d_in[16];
  const float* g1  = (const float*)d_in[17]; const float* lb1 = (const float*)d_in[18];
  const float* g2  = (const float*)d_in[19]; const float* lb2 = (const float*)d_in[20];

  char* ws = (char*)d_ws;
  f16*   Qn     = (f16*)(ws + 0);
  f16*   Kn     = (f16*)(ws + 12800000L);
  f16*   Vn     = (f16*)(ws + 25600000L);
  float* Skip   = (float*)(ws + 38400000L);
  int*   offs   = (int*)(ws + 64000000L);      // 200,004 B (pad to 200,192)
  f16*   WhAll  = (f16*)(ws + 64200192L);      // 229,376 B; overlays cursor (dead after CSR)
  int*   cursor = (int*)(ws + 64200192L);
  int*   counts = (int*)(ws + 64429568L);      // 200,000 B
  int*   elist  = (int*)(ws + 64629760L);      // 3,200,000 B
  f16*   emat   = (f16*)(ws + 67829760L);      // 204,800,000 B (dst-sorted)
  float* node1  = (float*)(ws + 272629760L);   // 25,600,000 B
  int*   srcs   = (int*)(ws + 272629760L);     // overlays node1 (dead before post_ln1)
  float* hid    = (float*)(ws + 38400000L);    // reuse Skip (dead after post_ln1)
  float* h2     = (float*)(ws + 0);            // reuse Qn/Kn (dead after attn_fused)
  float* attn   = (float*)d_out;               // staging; overwritten by final post_ln

  (void)hipMemsetAsync(counts, 0, N_NODES * sizeof(int), stream);
  hist_k<<<1024, 256, 0, stream>>>(ei, counts);
  scan_k<<<1, 1024, 0, stream>>>(counts, offs, cursor);
  scatter_k<<<1024, 256, 0, stream>>>(ei, cursor, elist, srcs);
  convert7<<<112, 1024, 0, stream>>>(Wq, Wk, Wv, Wsk, We, W1, W2, WhAll);

  node4_v4<<<NODE_TILES, 256, 0, stream>>>(x0, WhAll, bq, bk, bv, bsk, Qn, Kn, Vn, Skip);
  gemm_v4g<1><<<2500, 256, 0, stream>>>(ea, (long)N_EDGES, EDGE_TILES, elist,
                                        WhAll + 4 * 16384, be, emat);
  attn_fused<<<12500, 256, 0, stream>>>(offs, srcs, emat, Qn, Kn, Vn, attn);
  post_ln<<<12500, 256, 0, stream>>>(attn, Skip, x0, g1, lb1, node1);
  gemm_v4<0, 1><<<NODE_TILES, 256, 0, stream>>>(node1, (long)N_NODES, NODE_TILES,
                                                WhAll + 5 * 16384, b1, hid);
  gemm_v4<0, 0><<<NODE_TILES, 256, 0, stream>>>(hid, (long)N_NODES, NODE_TILES,
                                                WhAll + 6 * 16384, b2, h2);
  post_ln<<<12500, 256, 0, stream>>>(h2, nullptr, node1, g2, lb2, (float*)d_out);
}